// Round 5
// baseline (291.776 us; speedup 1.0000x reference)
//
#include <hip/hip_runtime.h>
#include <hip/hip_fp16.h>

// Problem constants (match reference)
#define NC 128
#define NS 2048
#define NX 256
#define NZ 512
#define NROWS (NX * NZ)      // 131072 output pixels
#define NCOLS (NS * NC)      // 262144 rhs rows
#define RUN 8                // contiguous nnz per lane
#define WAVE_NNZ (RUN * 64)  // 512 nnz per tile
#define NT 4                 // tiles per wave (pipelined)
#define WAVE_RANGE (NT * WAVE_NNZ)   // 2048 nnz per wave
#define NSLOTS 64            // LDS row-accumulator slots per wave

// NOTE: harness passes ALL integer inputs as int32.
// NOTE (r3): nontemporal on the 8B gathers REGRESSED (+200MB) — L2 thrash.
// NOTE (r4): too-few waves (16/CU) -> occupancy-starved at one-shot struct.
// NOTE (r5): per-lane GLOBAL atomics: HBM-side RMW, 146MB writes. Sink must
//            be LDS-local; global atomics only at wave boundaries.
// NOTE (r6): FAILED: "VGPR-starved MLP" — caps/sched_barrier didn't move it.
// NOTE (r7): NT loads on read-once streams: FETCH 146->113MB, dur only -11us.
// NOTE (r8): __builtin_nontemporal_load needs ext_vector_type, not int4.
// NOTE (r9): FAILED: L1-bypass (agent-scope atomic load) on gathers — null.
// NOTE (r10): surviving model: latency x insufficient-concurrency. One-shot
//            waves have ~40% memory-duty-cycle (issue 14 loads, vmcnt(0),
//            then pure VALU/LDS/barrier/epilogue with nothing in flight).
//            134 in-flight/CU @ ~650cy = 0.2 lines/cy = 137us. Restructure:
//            4 pipelined tiles/wave, no barriers, per-wave LDS, static
//            double-buffers, phases pinned with sched_barrier(0).

struct alignas(8) Half4 { __half2 lo, hi; };

typedef int   vint4   __attribute__((ext_vector_type(4)));
typedef float vfloat4 __attribute__((ext_vector_type(4)));

__device__ __forceinline__ int4 nt_load_i4(const int* p) {
    vint4 t = __builtin_nontemporal_load((const vint4*)p);
    return make_int4(t.x, t.y, t.z, t.w);
}
__device__ __forceinline__ float4 nt_load_f4(const float* p) {
    vfloat4 t = __builtin_nontemporal_load((const vfloat4*)p);
    return make_float4(t.x, t.y, t.z, t.w);
}

// Kernel 1: pack x (B,K,NC,NS) into fp16 rhs[j], j = s*NC + c.
__global__ void pack_rhs_kernel(const float* __restrict__ x,
                                Half4* __restrict__ rhs) {
    int j = blockIdx.x * blockDim.x + threadIdx.x;
    if (j >= NCOLS) return;
    int c = j >> 11;         // 0..127
    int s = j & (NS - 1);    // 0..2047, consecutive within wave
    int base = c * NS + s;   // coalesced across lanes
    Half4 h;
    h.lo = __float22half2_rn(make_float2(x[base],               x[base + 1 * NC * NS]));
    h.hi = __float22half2_rn(make_float2(x[base + 2 * NC * NS], x[base + 3 * NC * NS]));
    rhs[s * NC + c] = h;
}

__device__ __forceinline__ void global_flush(float* __restrict__ out, int r, float4 a) {
    int ix = r >> 9;          // r / NZ
    int iz = r & (NZ - 1);    // r % NZ
    int o = iz * NX + ix;     // out[b, iz, ix]
    atomicAdd(&out[0 * NROWS + o], a.x);
    atomicAdd(&out[1 * NROWS + o], a.y);
    atomicAdd(&out[2 * NROWS + o], a.z);
    atomicAdd(&out[3 * NROWS + o], a.w);
}

__device__ __forceinline__ void load_streams(const float* __restrict__ vals,
                                             const int* __restrict__ cols,
                                             const int* __restrict__ rows,
                                             int nnz, int tb, int lane,
                                             float4 (&v)[2], int4 (&c4)[2], int4 (&r4)[2]) {
    int lb = tb + lane * RUN;
    if (tb + WAVE_NNZ <= nnz) {
        #pragma unroll
        for (int q = 0; q < 2; ++q) c4[q] = nt_load_i4(cols + lb + 4 * q);
        #pragma unroll
        for (int q = 0; q < 2; ++q) v[q]  = nt_load_f4(vals + lb + 4 * q);
        #pragma unroll
        for (int q = 0; q < 2; ++q) r4[q] = nt_load_i4(rows + lb + 4 * q);
    } else {
        #pragma unroll
        for (int q = 0; q < 2; ++q) {
            #pragma unroll
            for (int k = 0; k < 4; ++k) {
                int e = lb + 4 * q + k;
                int ec = e < nnz ? e : (nnz - 1);
                (&v[q].x)[k]  = e < nnz ? vals[ec] : 0.f;   // v=0: contributes nothing
                (&c4[q].x)[k] = cols[ec];
                (&r4[q].x)[k] = rows[ec];
            }
        }
    }
}

__device__ __forceinline__ void issue_gathers(const Half4* __restrict__ rhs,
                                              const int4 (&c4)[2], Half4 (&g)[RUN]) {
    #pragma unroll
    for (int q = 0; q < 2; ++q) {
        g[4 * q + 0] = rhs[c4[q].x];
        g[4 * q + 1] = rhs[c4[q].y];
        g[4 * q + 2] = rhs[c4[q].z];
        g[4 * q + 3] = rhs[c4[q].w];
    }
}

__device__ __forceinline__ void accum_tile(const float4 (&v)[2], const int4 (&r4)[2],
                                           const Half4 (&g)[RUN],
                                           int rfirst, int& cur, float4& acc,
                                           float* __restrict__ out,
                                           float (*slw)[4]) {
    #pragma unroll
    for (int j = 0; j < RUN; ++j) {
        int   rj = (&r4[j >> 2].x)[j & 3];
        float vj = (&v[j >> 2].x)[j & 3];
        float2 lo = __half22float2(g[j].lo);
        float2 hi = __half22float2(g[j].hi);
        if (rj != cur) {                 // rare: rows avg 128 nnz
            int s = cur - rfirst;
            if (s < NSLOTS) {
                atomicAdd(&slw[s][0], acc.x);
                atomicAdd(&slw[s][1], acc.y);
                atomicAdd(&slw[s][2], acc.z);
                atomicAdd(&slw[s][3], acc.w);
            } else {
                global_flush(out, cur, acc);   // span overflow: rare, correct
            }
            acc = make_float4(0.f, 0.f, 0.f, 0.f);
            cur = rj;
        }
        acc.x += vj * lo.x;
        acc.y += vj * lo.y;
        acc.z += vj * hi.x;
        acc.w += vj * hi.y;
    }
}

// Kernel 2 (r10): wave owns 2048 contiguous nnz = 4 tiles, software-pipelined:
//   prologue: streams(0); gathers(0); streams(1)
//   iter t:   gathers(t+1) [waits streams(t+1), implies gathers(t) done],
//             accumulate(t) [gathers(t+1) in flight], streams(t+2)
// No __syncthreads anywhere: LDS slots are per-wave private. Buffers are
// statically named (g0/g1 etc) — no runtime indexing (scratch hazard).
__global__ void __launch_bounds__(256, 4) spmm_seg_kernel(
        const float* __restrict__ vals,
        const int* __restrict__ cols,
        const int* __restrict__ rows,
        const Half4* __restrict__ rhs,
        float* __restrict__ out,
        int nnz) {
    __shared__ float sl[4][NSLOTS][4];   // 4KB per block, per-wave private

    int wv   = threadIdx.x >> 6;
    int lane = threadIdx.x & 63;
    int wid  = (blockIdx.x << 2) + wv;
    int wstart = wid * WAVE_RANGE;
    if (wstart >= nnz) return;
    int wend = wstart + WAVE_RANGE;
    if (wend > nnz) wend = nnz;

    float (*slw)[4] = sl[wv];

    int rfirst = rows[wstart];
    int rlast  = rows[wend - 1];

    // zero this wave's own slots (16B per lane); same-wave DS ordering is
    // program-order, no barrier needed.
    *(float4*)(&slw[lane][0]) = make_float4(0.f, 0.f, 0.f, 0.f);

    float4 v0[2], v1[2];
    int4   c0[2], c1[2], r0[2], r1[2];
    Half4  g0[RUN], g1[RUN];

    // ---- prologue ----
    load_streams(vals, cols, rows, nnz, wstart + 0 * WAVE_NNZ, lane, v0, c0, r0);
    __builtin_amdgcn_sched_barrier(0);
    issue_gathers(rhs, c0, g0);              // waits streams(0)
    __builtin_amdgcn_sched_barrier(0);
    load_streams(vals, cols, rows, nnz, wstart + 1 * WAVE_NNZ, lane, v1, c1, r1);
    __builtin_amdgcn_sched_barrier(0);

    int cur = rfirst;
    float4 acc = make_float4(0.f, 0.f, 0.f, 0.f);

    // ---- t = 0 ----  (tile0 in buf0, tile1 streams in buf1)
    issue_gathers(rhs, c1, g1);              // waits streams(1) => gathers(0) done
    __builtin_amdgcn_sched_barrier(0);
    accum_tile(v0, r0, g0, rfirst, cur, acc, out, slw);
    load_streams(vals, cols, rows, nnz, wstart + 2 * WAVE_NNZ, lane, v0, c0, r0);
    __builtin_amdgcn_sched_barrier(0);

    // ---- t = 1 ----  (tile1 in buf1, tile2 streams in buf0)
    issue_gathers(rhs, c0, g0);              // waits streams(2) => gathers(1) done
    __builtin_amdgcn_sched_barrier(0);
    accum_tile(v1, r1, g1, rfirst, cur, acc, out, slw);
    load_streams(vals, cols, rows, nnz, wstart + 3 * WAVE_NNZ, lane, v1, c1, r1);
    __builtin_amdgcn_sched_barrier(0);

    // ---- t = 2 ----  (tile2 in buf0, tile3 streams in buf1)
    issue_gathers(rhs, c1, g1);              // waits streams(3) => gathers(2) done
    __builtin_amdgcn_sched_barrier(0);
    accum_tile(v0, r0, g0, rfirst, cur, acc, out, slw);

    // ---- t = 3 ----  (tile3 in buf1)
    accum_tile(v1, r1, g1, rfirst, cur, acc, out, slw);

    // ---- final flush ----
    {
        int s = cur - rfirst;
        if (s < NSLOTS) {
            atomicAdd(&slw[s][0], acc.x);
            atomicAdd(&slw[s][1], acc.y);
            atomicAdd(&slw[s][2], acc.z);
            atomicAdd(&slw[s][3], acc.w);
        } else {
            global_flush(out, cur, acc);
        }
    }

    // ---- epilogue: one slot per lane (per-wave private, no barrier) ----
    int span = rlast - rfirst;
    if (lane <= span && lane < NSLOTS) {
        float ax = slw[lane][0];
        float ay = slw[lane][1];
        float az = slw[lane][2];
        float aw = slw[lane][3];
        int rr = rfirst + lane;
        int ix = rr >> 9;
        int iz = rr & (NZ - 1);
        int o = iz * NX + ix;
        if (lane == 0 || rr == rlast) {
            // boundary row: may be shared with neighbor wave
            atomicAdd(&out[0 * NROWS + o], ax);
            atomicAdd(&out[1 * NROWS + o], ay);
            atomicAdd(&out[2 * NROWS + o], az);
            atomicAdd(&out[3 * NROWS + o], aw);
        } else {
            // interior row: all its nnz are in this wave (rows sorted)
            out[0 * NROWS + o] = ax;
            out[1 * NROWS + o] = ay;
            out[2 * NROWS + o] = az;
            out[3 * NROWS + o] = aw;
        }
    }
}

// Fallback (workspace too small): inline bounds + direct fp32 gather from x.
__global__ void __launch_bounds__(256) spmm_direct_kernel(
        const float* __restrict__ x,
        const float* __restrict__ vals,
        const int* __restrict__ rows,
        const int* __restrict__ cols,
        int nnz,
        float* __restrict__ out) {
    int r = (blockIdx.x << 2) + (threadIdx.x >> 6);
    int lane = threadIdx.x & 63;
    int start, end;
    {
        int lo = 0, hi = nnz;
        while (lo < hi) { int mid = (lo + hi) >> 1; if (rows[mid] < r) lo = mid + 1; else hi = mid; }
        start = lo;
        hi = nnz;
        int key = r + 1;
        while (lo < hi) { int mid = (lo + hi) >> 1; if (rows[mid] < key) lo = mid + 1; else hi = mid; }
        end = lo;
    }
    float4 acc = {0.f, 0.f, 0.f, 0.f};
    for (int i = start + lane; i < end; i += 64) {
        float v = vals[i];
        int col = cols[i];
        int cc = col & (NC - 1);
        int ss = col >> 7;
        int b = cc * NS + ss;
        acc.x += v * x[b];
        acc.y += v * x[b + 1 * NC * NS];
        acc.z += v * x[b + 2 * NC * NS];
        acc.w += v * x[b + 3 * NC * NS];
    }
    #pragma unroll
    for (int off = 32; off >= 1; off >>= 1) {
        acc.x += __shfl_xor(acc.x, off, 64);
        acc.y += __shfl_xor(acc.y, off, 64);
        acc.z += __shfl_xor(acc.z, off, 64);
        acc.w += __shfl_xor(acc.w, off, 64);
    }
    if (lane < 4) {
        float o = (lane == 0) ? acc.x : (lane == 1) ? acc.y : (lane == 2) ? acc.z : acc.w;
        int ix = r >> 9;
        int iz = r & (NZ - 1);
        out[lane * NROWS + iz * NX + ix] = o;
    }
}

extern "C" void kernel_launch(void* const* d_in, const int* in_sizes, int n_in,
                              void* d_out, int out_size, void* d_ws, size_t ws_size,
                              hipStream_t stream) {
    const float* x        = (const float*)d_in[0];
    const float* csr_vals = (const float*)d_in[1];
    const int*   csr_rows = (const int*)d_in[2];   // int32 per harness contract
    const int*   csr_cols = (const int*)d_in[3];
    float* out = (float*)d_out;
    int nnz = in_sizes[1];

    size_t need = (size_t)NCOLS * sizeof(Half4);   // 2MB
    if (ws_size >= need) {
        Half4* rhs = (Half4*)d_ws;
        hipMemsetAsync(out, 0, (size_t)out_size * sizeof(float), stream);
        pack_rhs_kernel<<<(NCOLS + 255) / 256, 256, 0, stream>>>(x, rhs);
        int per_block = 4 * WAVE_RANGE;            // 4 waves x 2048 nnz
        int nblocks = (nnz + per_block - 1) / per_block;   // 2048 blocks, 8192 waves
        spmm_seg_kernel<<<nblocks, 256, 0, stream>>>(csr_vals, csr_cols, csr_rows,
                                                     rhs, out, nnz);
    } else {
        spmm_direct_kernel<<<NROWS / 4, 256, 0, stream>>>(x, csr_vals, csr_rows, csr_cols, nnz, out);
    }
}